// Round 2
// baseline (1454.030 us; speedup 1.0000x reference)
//
#include <hip/hip_runtime.h>
#include <hip/hip_cooperative_groups.h>
#include <math.h>

namespace cg = cooperative_groups;
typedef float4 f4;
typedef float2 f2;

#define NT 512          // 8 waves/block; wave-local dataflow: wave w owns rows 4w..4w+3
#define RB 32           // rows per block; GRID=256 (cooperative cap)

// ---------------- workspace float offsets (weights + partials only) -------
#define WS_WR    0          // WR[128][256]: [k][0:128]=W2T row k, [k][128:256]=R row k
#define WS_PART  32768      // [10][256] err partials
#define WS_TOTAL 35328

// ---------------- LDS float offsets (152.3 KB) ----------------------------
#define L_W1T   0           // [32][128]  W1T[j][h] = W1[h][j]
#define L_C3T   4096        // [32][132]  C3T[c][b] = C3[b][c]
#define L_PT    8320        // [32][36]   PT[c][q] = P[q][c]
#define L_XW    9472        // [8][32][4]  per-wave x, k-major: XW[w][k][r]
#define L_H1W   10496       // [8][128][4] per-wave h1, h-major: H1W[w][h][r]
#define L_H2W   14592       // [8][128][4] per-wave h2
#define L_KZ    18688       // [7][32][36] k_z, pitch 36
#define L_KL    26752       // [7][32]     k_l
#define L_YZ    26976       // [32][36]    y_z
#define L_Y1Z   28128       // [32][36]    y1_z
#define L_YL    29280       // [32]
#define L_Y1L   29312       // [32]
#define L_B1    29344
#define L_B2    29472
#define L_C0    29600
#define L_GS    29632       // [8][32]
#define L_AAUG  29888       // [8][16]
#define L_AINVG 30016       // [8][32]
#define L_MISC  30272       // [0]=trP
#define L_S     30276       // [4 pairs][32 cg][68] partial-sum exchange (pad 68: 4-way)
#define LDS_FLOATS (30276 + 4*32*68)
#define L_RED   L_H1W       // [8] alias — H1W dead during error reduction
#define L_P     L_H2W       // [32][32] init-only alias
#define L_IP    (L_H2W + 1024) // [32][32] init-only alias
#define L_IPW3  L_KZ        // [32][128] init-only alias

__device__ const float ACO[5][5] = {
  { 0.2f, 0.f, 0.f, 0.f, 0.f },
  { (float)(3.0/40.0), (float)(9.0/40.0), 0.f, 0.f, 0.f },
  { (float)(44.0/45.0), (float)(-56.0/15.0), (float)(32.0/9.0), 0.f, 0.f },
  { (float)(19372.0/6561.0), (float)(-25360.0/2187.0), (float)(64448.0/6561.0), (float)(-212.0/729.0), 0.f },
  { (float)(9017.0/3168.0), (float)(-355.0/33.0), (float)(46732.0/5247.0), (float)(49.0/176.0), (float)(-5103.0/18656.0) }
};

#define B1C ((float)(35.0/384.0))
#define B3C ((float)(500.0/1113.0))
#define B4C ((float)(125.0/192.0))
#define B5C ((float)(-2187.0/6784.0))
#define B6C ((float)(11.0/84.0))

#define E1C ((float)(35.0/384.0 - 5179.0/57600.0))
#define E3C ((float)(500.0/1113.0 - 7571.0/16695.0))
#define E4C ((float)(125.0/192.0 - 393.0/640.0))
#define E5C ((float)(-2187.0/6784.0 + 92097.0/339200.0))
#define E6C ((float)(11.0/84.0 - 187.0/2100.0))
#define E7C ((float)(-1.0/40.0))

__device__ __forceinline__ f4 ld4(const float* p){ return *(const f4*)p; }
__device__ __forceinline__ void st4(float* p, f4 v){ *(f4*)p = v; }

// wave-local assemble: x = y + dtc*sum_p co[p]*k[p] -> XW[w] (k-major).
__device__ __forceinline__ void assemble_x(float* lds, int tid, float dtc,
                                           const float* co, int np)
{
  const int w = tid >> 6, lane = tid & 63;
  const int r = lane >> 4;            // 0..3 local row
  const int c = (lane << 1) & 31;     // even col
  const int o = (4 * w + r) * 36 + c;
  f2 y = *(const f2*)&lds[L_YZ + o];
  float sx = 0.f, sy = 0.f;
  for (int p = 0; p < np; p++){
    f2 kv = *(const f2*)&lds[L_KZ + p * 1152 + o];
    sx += co[p] * kv.x; sy += co[p] * kv.y;
  }
  float* XWp = &lds[L_XW + w * 128];
  XWp[(c + 0) * 4 + r] = y.x + dtc * sx;
  XWp[(c + 1) * 4 + r] = y.y + dtc * sy;
}

// full f-eval. Phase 2 is k-split across wave pairs (2p: k[0,64), 2p+1: k[64,128)),
// each pair jointly covers 8 rows; partials exchanged via padded LDS scratch.
// WR traffic per CU per eval: 512 KB (was 1 MB) -> below per-CU L2 BW share.
__device__ void eval_f(float* lds, const float* __restrict__ ws, int tid,
                       float trP, int kout)
{
  const int w = tid >> 6, lane = tid & 63;
  const int cg = lane & 31, kh = lane >> 5;
  const int p  = w >> 1;             // pair id 0..3 (rows 8p..8p+7)
  const int kg = w & 1;              // k-group: 0 -> [0,64), 1 -> [64,128)
  float* XWp = &lds[L_XW  + w * 128];
  float* H1p = &lds[L_H1W + w * 512];
  float* H1e = &lds[L_H1W + (2 * p) * 512];       // rows 8p..8p+3
  float* H1o = &lds[L_H1W + (2 * p + 1) * 512];   // rows 8p+4..8p+7
  float* H2w = &lds[L_H2W + w * 512];

  // ---- issue first WR prefetch NOW: L2 latency hides under phase 1 ----
  const f4* WR4 = (const f4*)&ws[WS_WR];   // row k = 64 f4: [0:32)=W2T, [32:64)=R
  const int kb = kg * 64 + kh * 32;
  f4 wb[4], rb[4];
#pragma unroll
  for (int u = 0; u < 4; u++){
    wb[u] = WR4[(kb + u) * 64 + cg];
    rb[u] = WR4[(kb + u) * 64 + 32 + cg];
  }

  // ---- phase 1: h1 = relu(x @ W1^T + b1) -> H1W[w] (own 4 rows) ----
  float a1[4][4];
#pragma unroll
  for (int i = 0; i < 4; i++)
#pragma unroll
    for (int j = 0; j < 4; j++) a1[i][j] = 0.f;
#pragma unroll 4
  for (int t = 0; t < 16; t++){
    const int k = kh * 16 + t;
    f4 xv = ld4(&XWp[k * 4]);                       // broadcast (4 rows)
    f4 wv = ld4(&lds[L_W1T + k * 128 + 4 * cg]);
    const float* ap = (const float*)&xv;
    const float* bp = (const float*)&wv;
#pragma unroll
    for (int i = 0; i < 4; i++)
#pragma unroll
      for (int j = 0; j < 4; j++) a1[i][j] += bp[i] * ap[j];
  }
#pragma unroll
  for (int i = 0; i < 4; i++)
#pragma unroll
    for (int j = 0; j < 4; j++) a1[i][j] += __shfl_xor(a1[i][j], 32);
  if (kh == 0){
    f4 b1v = ld4(&lds[L_B1 + 4 * cg]);
    const float* b1p = (const float*)&b1v;
#pragma unroll
    for (int i = 0; i < 4; i++){
      f4 hv; float* hp = (float*)&hv;
#pragma unroll
      for (int j = 0; j < 4; j++) hp[j] = fmaxf(a1[i][j] + b1p[i], 0.f);
      st4(&H1p[(4 * cg + i) * 4], hv);
    }
  }
  __syncthreads();                   // barrier #1: H1 of both pair-waves visible

  // ---- phase 2: ah = h1@W2^T, at = m1^T R over this wave's 64-k range,
  //      8 rows (pair's rows), 8 groups of 4 k ----
  float ah[4][8], at[4][8];
#pragma unroll
  for (int i = 0; i < 4; i++)
#pragma unroll
    for (int j = 0; j < 8; j++){ ah[i][j] = 0.f; at[i][j] = 0.f; }
#pragma unroll 1
  for (int g = 0; g < 8; g++){
    f4 wc[4], rc[4];
#pragma unroll
    for (int u = 0; u < 4; u++){ wc[u] = wb[u]; rc[u] = rb[u]; }
    if (g < 7){
      const int kn = kb + (g + 1) * 4;
#pragma unroll
      for (int u = 0; u < 4; u++){
        wb[u] = WR4[(kn + u) * 64 + cg];
        rb[u] = WR4[(kn + u) * 64 + 32 + cg];
      }
    }
#pragma unroll
    for (int u = 0; u < 4; u++){
      const int k = kb + g * 4 + u;
      f4 ae = ld4(&H1e[k * 4]);                     // broadcast rows 8p..8p+3
      f4 ao = ld4(&H1o[k * 4]);                     // broadcast rows 8p+4..8p+7
      const float* aep = (const float*)&ae;
      const float* aop = (const float*)&ao;
      const float* wp = (const float*)&wc[u];
      const float* rp = (const float*)&rc[u];
      float me[4], mo[4];
#pragma unroll
      for (int j = 0; j < 4; j++){
        me[j] = (aep[j] > 0.f) ? 1.f : 0.f;
        mo[j] = (aop[j] > 0.f) ? 1.f : 0.f;
      }
#pragma unroll
      for (int i = 0; i < 4; i++){
#pragma unroll
        for (int j = 0; j < 4; j++){
          ah[i][j]     += wp[i] * aep[j];
          at[i][j]     += rp[i] * me[j];
          ah[i][4 + j] += wp[i] * aop[j];
          at[i][4 + j] += rp[i] * mo[j];
        }
      }
    }
  }
  // intra-wave kh reduce (two 32-k halves -> wave's 64-k sums)
#pragma unroll
  for (int i = 0; i < 4; i++)
#pragma unroll
    for (int j = 0; j < 8; j++){
      ah[i][j] += __shfl_xor(ah[i][j], 32);
      at[i][j] += __shfl_xor(at[i][j], 32);
    }

  // ---- cross-wave 2-way k-reduce via padded LDS scratch ----
  float* S = &lds[L_S + (p * 32 + cg) * 68];
  if (kg == 1 && kh == 0){
#pragma unroll
    for (int i = 0; i < 4; i++){
      f4 a, b; float* apx = (float*)&a; float* bpx = (float*)&b;
#pragma unroll
      for (int j = 0; j < 4; j++){ apx[j] = ah[i][j]; bpx[j] = ah[i][4 + j]; }
      st4(&S[i * 8], a); st4(&S[i * 8 + 4], b);
#pragma unroll
      for (int j = 0; j < 4; j++){ apx[j] = at[i][j]; bpx[j] = at[i][4 + j]; }
      st4(&S[32 + i * 8], a); st4(&S[32 + i * 8 + 4], b);
    }
  }
  __syncthreads();                   // barrier #2: partials visible

  if (kg == 0){
    // add partner's partials (both kh halves: same addrs -> broadcast)
#pragma unroll
    for (int i = 0; i < 4; i++){
      f4 a = ld4(&S[i * 8]), b = ld4(&S[i * 8 + 4]);
      const float* apx = (const float*)&a; const float* bpx = (const float*)&b;
#pragma unroll
      for (int j = 0; j < 4; j++){ ah[i][j] += apx[j]; ah[i][4 + j] += bpx[j]; }
      a = ld4(&S[32 + i * 8]); b = ld4(&S[32 + i * 8 + 4]);
      apx = (const float*)&a; bpx = (const float*)&b;
#pragma unroll
      for (int j = 0; j < 4; j++){ at[i][j] += apx[j]; at[i][4 + j] += bpx[j]; }
    }
    f4 b2v = ld4(&lds[L_B2 + 4 * cg]);
    const float* b2p = (const float*)&b2v;
    float h2v[4][8]; float dl[8] = {0.f,0.f,0.f,0.f,0.f,0.f,0.f,0.f};
#pragma unroll
    for (int i = 0; i < 4; i++)
#pragma unroll
      for (int j = 0; j < 8; j++){
        float pre = ah[i][j] + b2p[i];
        float hv = fmaxf(pre, 0.f);
        h2v[i][j] = hv;
        if (pre > 0.f) dl[j] += at[i][j];
      }
    if (kh){                         // kh=1 holds duplicate cols: zero before reduce
#pragma unroll
      for (int j = 0; j < 8; j++) dl[j] = 0.f;
    }
#pragma unroll
    for (int mk = 1; mk < 64; mk <<= 1){
#pragma unroll
      for (int j = 0; j < 8; j++) dl[j] += __shfl_xor(dl[j], mk, 64);
    }
    if (kh == 0){
      float* H2e = &lds[L_H2W + (2 * p) * 512];
      float* H2o = &lds[L_H2W + (2 * p + 1) * 512];
#pragma unroll
      for (int i = 0; i < 4; i++){
        f4 a, b; float* apx = (float*)&a; float* bpx = (float*)&b;
#pragma unroll
        for (int j = 0; j < 4; j++){ apx[j] = h2v[i][j]; bpx[j] = h2v[i][4 + j]; }
        st4(&H2e[(4 * cg + i) * 4], a);
        st4(&H2o[(4 * cg + i) * 4], b);
      }
    }
    if (lane == 0){
#pragma unroll
      for (int j = 0; j < 8; j++)
        lds[L_KL + kout * 32 + 8 * p + j] = dl[j] + trP;
    }
  }
  __syncthreads();                   // barrier #3: H2/KL visible to all waves

  // ---- phase 3: dz = -(h2 @ C3 + c0 + x @ P) -> KZ rows of this wave ----
  float a3[4] = {0.f, 0.f, 0.f, 0.f};
  const int bb = kh * 64;
#pragma unroll 4
  for (int t = 0; t < 16; t++){
    f4 cv = ld4(&lds[L_C3T + cg * 132 + bb + 4 * t]);
    const float* cp = (const float*)&cv;
#pragma unroll
    for (int u = 0; u < 4; u++){
      f4 av = ld4(&H2w[(bb + 4 * t + u) * 4]);      // broadcast
      const float* ap = (const float*)&av;
#pragma unroll
      for (int j = 0; j < 4; j++) a3[j] += ap[j] * cp[u];
    }
  }
  const int qq = kh * 16;
#pragma unroll
  for (int t = 0; t < 4; t++){
    f4 pv = ld4(&lds[L_PT + cg * 36 + qq + 4 * t]);
    const float* pp = (const float*)&pv;
#pragma unroll
    for (int u = 0; u < 4; u++){
      f4 av = ld4(&XWp[(qq + 4 * t + u) * 4]);      // broadcast
      const float* ap = (const float*)&av;
#pragma unroll
      for (int j = 0; j < 4; j++) a3[j] += ap[j] * pp[u];
    }
  }
#pragma unroll
  for (int j = 0; j < 4; j++) a3[j] += __shfl_xor(a3[j], 32);
  if (kh == 0){
    float c0v = lds[L_C0 + cg];
#pragma unroll
    for (int j = 0; j < 4; j++)
      lds[L_KZ + kout * 1152 + (4 * w + j) * 36 + cg] = -(a3[j] + c0v);
  }
}

__global__ void __launch_bounds__(NT, 1)
qpnf_kernel(const float* __restrict__ z, const float* __restrict__ Gw,
            const float* __restrict__ W1g, const float* __restrict__ b1g,
            const float* __restrict__ W2g, const float* __restrict__ b2g,
            const float* __restrict__ W3g, const float* __restrict__ b3g,
            const float* __restrict__ Tg, float* __restrict__ out,
            float* __restrict__ ws)
{
  __shared__ float lds[LDS_FLOATS];
  const int tid = threadIdx.x;
  const int bid = blockIdx.x;
  const int r0 = bid * RB;
  cg::grid_group grid = cg::this_grid();

  // ================= init =================
  for (int i = 0; i < 8; i++){                // W1T[j][h] = W1[h][j]
    int idx = tid + i * NT;
    int h = idx >> 5, j = idx & 31;
    lds[L_W1T + j * 128 + h] = W1g[idx];
  }
  if (tid < 128){ lds[L_B1 + tid] = b1g[tid]; lds[L_B2 + tid] = b2g[tid]; }
  if (tid < 256) lds[L_GS + tid] = Gw[tid];
  __syncthreads();

  if (tid < 64){                              // A = G G^T (8x8), augmented
    int i = tid >> 3, j = tid & 7;
    float s = 0.f;
    for (int k = 0; k < 32; k++) s += lds[L_GS + i * 32 + k] * lds[L_GS + j * 32 + k];
    lds[L_AAUG + i * 16 + j] = s;
    lds[L_AAUG + i * 16 + 8 + j] = (i == j) ? 1.f : 0.f;
  }
  __syncthreads();
  if (tid == 0){                              // Gauss-Jordan, partial pivoting
    float* A = &lds[L_AAUG];
    for (int c = 0; c < 8; c++){
      int p = c; float mx = fabsf(A[c * 16 + c]);
      for (int r = c + 1; r < 8; r++){
        float v = fabsf(A[r * 16 + c]);
        if (v > mx){ mx = v; p = r; }
      }
      if (p != c)
        for (int q = 0; q < 16; q++){ float t = A[c*16+q]; A[c*16+q] = A[p*16+q]; A[p*16+q] = t; }
      float pv = 1.0f / A[c * 16 + c];
      for (int q = 0; q < 16; q++) A[c * 16 + q] *= pv;
      for (int r = 0; r < 8; r++) if (r != c){
        float fct = A[r * 16 + c];
        for (int q = 0; q < 16; q++) A[r * 16 + q] -= fct * A[c * 16 + q];
      }
    }
  }
  __syncthreads();
  if (tid < 256){                              // AinvG[m][d]
    int m = tid >> 5, d = tid & 31;
    float s = 0.f;
    for (int q = 0; q < 8; q++) s += lds[L_AAUG + m * 16 + 8 + q] * lds[L_GS + q * 32 + d];
    lds[L_AINVG + m * 32 + d] = s;
  }
  __syncthreads();
  for (int i4 = 0; i4 < 2; i4++){              // P = G^T AinvG (alias in H2W)
    int idx = tid + i4 * NT;
    int i = idx >> 5, j = idx & 31;
    float s = 0.f;
    for (int m = 0; m < 8; m++) s += lds[L_GS + m * 32 + i] * lds[L_AINVG + m * 32 + j];
    lds[L_P + i * 32 + j] = s;
  }
  __syncthreads();
  float* IPl = &lds[L_IP];                     // IP aliases H2W+1024 during init
  for (int i4 = 0; i4 < 2; i4++){
    int idx = tid + i4 * NT;
    int i = idx >> 5, j = idx & 31;
    IPl[i * 32 + j] = ((i == j) ? 1.f : 0.f) - lds[L_P + i * 32 + j];
  }
  if (tid == 0){
    float s = 0.f;
    for (int i = 0; i < 32; i++) s += lds[L_P + i * 32 + i];
    lds[L_MISC] = s;                           // trP
  }
  __syncthreads();
  for (int i4 = 0; i4 < 8; i4++){              // C3T[c][b] = sum_i W3[i][b] IP[i][c]
    int idx = tid + i4 * NT;
    int b = idx & 127, c = idx >> 7;
    float s = 0.f;
    for (int i = 0; i < 32; i++) s += W3g[i * 128 + b] * IPl[i * 32 + c];
    lds[L_C3T + c * 132 + b] = s;
  }
  for (int i4 = 0; i4 < 2; i4++){              // PT[c][q] = P[q][c]
    int idx = tid + i4 * NT;
    int c = idx >> 5, q = idx & 31;
    lds[L_PT + c * 36 + q] = lds[L_P + q * 32 + c];
  }
  if (tid < 32){                               // c0 = b3 @ IP
    float s = 0.f;
    for (int i = 0; i < 32; i++) s += b3g[i] * IPl[i * 32 + tid];
    lds[L_C0 + tid] = s;
  }
  for (int i4 = 0; i4 < 8; i4++){              // IPW3[j][b] (aliases KZ)
    int idx = tid + i4 * NT;
    int j = idx >> 7, b = idx & 127;
    float s = 0.f;
    for (int k = 0; k < 32; k++) s += IPl[j * 32 + k] * W3g[k * 128 + b];
    lds[L_IPW3 + j * 128 + b] = s;
  }
  __syncthreads();
  if (bid < 128 && tid < 128){                 // R row a=bid -> WR[a][128+b]
    int a = bid;
    float s = 0.f;
    for (int j = 0; j < 32; j++) s += W1g[a * 32 + j] * lds[L_IPW3 + j * 128 + tid];
    ws[WS_WR + a * 256 + 128 + tid] = s * W2g[tid * 128 + a];
  }
  if (bid >= 128 && tid < 128){                // W2T row a -> WR[a][b]
    int a = bid - 128;
    ws[WS_WR + a * 256 + tid] = W2g[tid * 128 + a];
  }
  if (tid < 256){                              // y0 = [z, 0] -> LDS
    const int r = tid >> 3, jj = (tid & 7) * 4;
    st4(&lds[L_YZ + r * 36 + jj], ld4(&z[(r0 + r) * 32 + jj]));
  }
  if (tid < RB) lds[L_YL + tid] = 0.f;

  const float trP = lds[L_MISC];
  const float t1 = 2.0f * Tg[0];

  grid.sync();

  // ================= main adaptive RK loop =================
  float t_cur = 0.f, dt_cur = 0.25f;
  bool prev_acc = false;

  for (int step = 0; step < 10; step++){
    if (t_cur >= t1 - 1e-9f) break;            // uniform across grid
    const float dtc = fminf(dt_cur, t1 - t_cur);

    // stages 1..6
    for (int s = 1; s <= 6; s++){
      if (s == 1 && step > 0){
        if (prev_acc){                         // FSAL: k1 = previous k7 (wave-local)
          const int w = tid >> 6, lane = tid & 63;
          const int r = lane >> 4, c = (lane << 1) & 31;
          const int o = (4 * w + r) * 36 + c;
          *(f2*)&lds[L_KZ + o] = *(const f2*)&lds[L_KZ + 6 * 1152 + o];
          if (lane < 4) lds[L_KL + 4 * w + lane] = lds[L_KL + 6 * 32 + 4 * w + lane];
        }                                       // rejected: k1 = f(y) unchanged
        continue;
      }
      assemble_x(lds, tid, dtc, ACO[s >= 2 ? s - 2 : 0], s - 1);
      eval_f(lds, ws, tid, trP, s - 1);
    }

    // stage 7: y1, k7 = f(y1), error estimate
    __syncthreads();                           // all waves' KZ/KL visible
    if (tid < 256){
      const int r = tid >> 3, jj = (tid & 7) * 4;
      const int o = r * 36 + jj;
      f4 y   = ld4(&lds[L_YZ + o]);
      f4 k1v = ld4(&lds[L_KZ + 0 * 1152 + o]);
      f4 k3v = ld4(&lds[L_KZ + 2 * 1152 + o]);
      f4 k4v = ld4(&lds[L_KZ + 3 * 1152 + o]);
      f4 k5v = ld4(&lds[L_KZ + 4 * 1152 + o]);
      f4 k6v = ld4(&lds[L_KZ + 5 * 1152 + o]);
      f4 x;
      x.x = y.x + dtc * (B1C*k1v.x + B3C*k3v.x + B4C*k4v.x + B5C*k5v.x + B6C*k6v.x);
      x.y = y.y + dtc * (B1C*k1v.y + B3C*k3v.y + B4C*k4v.y + B5C*k5v.y + B6C*k6v.y);
      x.z = y.z + dtc * (B1C*k1v.z + B3C*k3v.z + B4C*k4v.z + B5C*k5v.z + B6C*k6v.z);
      x.w = y.w + dtc * (B1C*k1v.w + B3C*k3v.w + B4C*k4v.w + B5C*k5v.w + B6C*k6v.w);
      st4(&lds[L_Y1Z + o], x);
      float* XWp = &lds[L_XW + (r >> 2) * 128];   // scatter into owning wave's XW
      const int rr = r & 3;
      XWp[(jj + 0) * 4 + rr] = x.x;
      XWp[(jj + 1) * 4 + rr] = x.y;
      XWp[(jj + 2) * 4 + rr] = x.z;
      XWp[(jj + 3) * 4 + rr] = x.w;
    }
    if (tid < RB){
      float s = B1C * lds[L_KL + 0*32 + tid] + B3C * lds[L_KL + 2*32 + tid]
              + B4C * lds[L_KL + 3*32 + tid] + B5C * lds[L_KL + 4*32 + tid]
              + B6C * lds[L_KL + 5*32 + tid];
      lds[L_Y1L + tid] = lds[L_YL + tid] + dtc * s;
    }
    __syncthreads();                           // XW scatter was cross-wave
    eval_f(lds, ws, tid, trP, 6);
    __syncthreads();                           // all waves' k7 visible

    float sacc = 0.f;
    if (tid < 256){
      const int r = tid >> 3, jj = (tid & 7) * 4;
      const int o = r * 36 + jj;
      f4 k1v = ld4(&lds[L_KZ + 0 * 1152 + o]);
      f4 k3v = ld4(&lds[L_KZ + 2 * 1152 + o]);
      f4 k4v = ld4(&lds[L_KZ + 3 * 1152 + o]);
      f4 k5v = ld4(&lds[L_KZ + 4 * 1152 + o]);
      f4 k6v = ld4(&lds[L_KZ + 5 * 1152 + o]);
      f4 k7v = ld4(&lds[L_KZ + 6 * 1152 + o]);
      f4 yv  = ld4(&lds[L_YZ + o]);
      f4 y1v = ld4(&lds[L_Y1Z + o]);
      float ev, tol, q;
      ev = dtc * (E1C*k1v.x + E3C*k3v.x + E4C*k4v.x + E5C*k5v.x + E6C*k6v.x + E7C*k7v.x);
      tol = 1e-5f + 1e-5f * fmaxf(fabsf(yv.x), fabsf(y1v.x)); q = ev / tol; sacc += q * q;
      ev = dtc * (E1C*k1v.y + E3C*k3v.y + E4C*k4v.y + E5C*k5v.y + E6C*k6v.y + E7C*k7v.y);
      tol = 1e-5f + 1e-5f * fmaxf(fabsf(yv.y), fabsf(y1v.y)); q = ev / tol; sacc += q * q;
      ev = dtc * (E1C*k1v.z + E3C*k3v.z + E4C*k4v.z + E5C*k5v.z + E6C*k6v.z + E7C*k7v.z);
      tol = 1e-5f + 1e-5f * fmaxf(fabsf(yv.z), fabsf(y1v.z)); q = ev / tol; sacc += q * q;
      ev = dtc * (E1C*k1v.w + E3C*k3v.w + E4C*k4v.w + E5C*k5v.w + E6C*k6v.w + E7C*k7v.w);
      tol = 1e-5f + 1e-5f * fmaxf(fabsf(yv.w), fabsf(y1v.w)); q = ev / tol; sacc += q * q;
    }
    if (tid < RB){
      float evl = dtc * (E1C * lds[L_KL + 0*32 + tid] + E3C * lds[L_KL + 2*32 + tid]
                + E4C * lds[L_KL + 3*32 + tid] + E5C * lds[L_KL + 4*32 + tid]
                + E6C * lds[L_KL + 5*32 + tid] + E7C * lds[L_KL + 6*32 + tid]);
      float toll = 1e-5f + 1e-5f * fmaxf(fabsf(lds[L_YL + tid]), fabsf(lds[L_Y1L + tid]));
      float ql = evl / toll; sacc += ql * ql;
    }
    // block reduction: wave butterflies + 8-wide LDS combine
#pragma unroll
    for (int mk = 1; mk < 64; mk <<= 1) sacc += __shfl_xor(sacc, mk, 64);
    if ((tid & 63) == 0) lds[L_RED + (tid >> 6)] = sacc;   // RED aliases dead H1W
    __syncthreads();
    if (tid == 0){
      float s = lds[L_RED+0] + lds[L_RED+1] + lds[L_RED+2] + lds[L_RED+3]
              + lds[L_RED+4] + lds[L_RED+5] + lds[L_RED+6] + lds[L_RED+7];
      ws[WS_PART + step * 256 + bid] = s;
    }

    grid.sync();

    // deterministic global reduction (every block, identical order)
    float ps = 0.f;
    if (tid < 256) ps = ws[WS_PART + step * 256 + tid];
#pragma unroll
    for (int mk = 1; mk < 64; mk <<= 1) ps += __shfl_xor(ps, mk, 64);
    if (tid < 256 && (tid & 63) == 0) lds[L_RED + (tid >> 6)] = ps;
    __syncthreads();
    const float errn = sqrtf((lds[L_RED+0] + lds[L_RED+1] + lds[L_RED+2] + lds[L_RED+3])
                             / 270336.0f);
    __syncthreads();             // protect RED(=H1W) before next phase-1 overwrite

    const bool accept = (errn <= 1.0f);
    if (accept){                               // wave-local y <- y1
      const int w = tid >> 6, lane = tid & 63;
      const int r = lane >> 4, c = (lane << 1) & 31;
      const int o = (4 * w + r) * 36 + c;
      *(f2*)&lds[L_YZ + o] = *(const f2*)&lds[L_Y1Z + o];
      if (lane < 4) lds[L_YL + 4 * w + lane] = lds[L_Y1L + 4 * w + lane];
      t_cur += dtc;
    }
    float fac = 0.9f * powf(errn, -0.2f);
    fac = fminf(fmaxf(fac, 0.2f), 10.0f);
    dt_cur = fminf(fmaxf(dtc * fac, 1e-6f), t1);
    prev_acc = accept;
  }

  // ---- output: yT[:, :d] ----
  __syncthreads();
  if (tid < 256){
    const int r = tid >> 3, jj = (tid & 7) * 4;
    st4(&out[(r0 + r) * 32 + jj], ld4(&lds[L_YZ + r * 36 + jj]));
  }
}

extern "C" void kernel_launch(void* const* d_in, const int* in_sizes, int n_in,
                              void* d_out, int out_size, void* d_ws, size_t ws_size,
                              hipStream_t stream)
{
  (void)in_sizes; (void)n_in; (void)out_size;
  const float* z  = (const float*)d_in[0];
  const float* Gw = (const float*)d_in[1];
  const float* W1 = (const float*)d_in[2];
  const float* b1 = (const float*)d_in[3];
  const float* W2 = (const float*)d_in[4];
  const float* b2 = (const float*)d_in[5];
  const float* W3 = (const float*)d_in[6];
  const float* b3 = (const float*)d_in[7];
  const float* T  = (const float*)d_in[8];
  float* out = (float*)d_out;
  float* ws  = (float*)d_ws;
  if (ws_size < (size_t)WS_TOTAL * sizeof(float)) return;

  void* args[] = { (void*)&z, (void*)&Gw, (void*)&W1, (void*)&b1, (void*)&W2,
                   (void*)&b2, (void*)&W3, (void*)&b3, (void*)&T, (void*)&out,
                   (void*)&ws };
  hipLaunchCooperativeKernel((const void*)qpnf_kernel, dim3(256), dim3(NT),
                             args, 0, stream);
}

// Round 3
// 1167.886 us; speedup vs baseline: 1.2450x; 1.2450x over previous
//
#include <hip/hip_runtime.h>
#include <hip/hip_cooperative_groups.h>
#include <math.h>

namespace cg = cooperative_groups;
typedef float4 f4;
typedef float2 f2;

#define NT 512          // 8 waves/block; wave-local dataflow: wave w owns rows 4w..4w+3
#define RB 32           // rows per block; GRID=256 (cooperative cap)

// ---------------- workspace float offsets (weights + partials only) -------
#define WS_WR    0          // WR[128][256]: [k][0:128]=W2T row k, [k][128:256]=R row k
#define WS_PART  32768      // [10][256] err partials
#define WS_TOTAL 35328

// ---------------- LDS float offsets (118.3 KB) ----------------------------
#define L_W1T   0           // [32][128]  W1T[j][h] = W1[h][j]
#define L_C3T   4096        // [32][132]  C3T[c][b] = C3[b][c]
#define L_PT    8320        // [32][36]   PT[c][q] = P[q][c]
#define L_XW    9472        // [8][32][4]  per-wave x, k-major: XW[w][k][r]
#define L_H1W   10496       // [8][128][4] per-wave h1, h-major: H1W[w][h][r]
#define L_H2W   14592       // [8][128][4] per-wave h2
#define L_KZ    18688       // [7][32][36] k_z, pitch 36
#define L_KL    26752       // [7][32]     k_l
#define L_YZ    26976       // [32][36]    y_z
#define L_Y1Z   28128       // [32][36]    y1_z
#define L_YL    29280       // [32]
#define L_Y1L   29312       // [32]
#define L_B1    29344
#define L_B2    29472
#define L_C0    29600
#define L_GS    29632       // [8][32]
#define L_AAUG  29888       // [8][16]
#define L_AINVG 30016       // [8][32]
#define L_MISC  30272       // [0]=trP
#define LDS_FLOATS 30276
#define L_RED   L_H1W       // [8] alias — H1W dead during error reduction
#define L_P     L_H2W       // [32][32] init-only alias
#define L_IP    (L_H2W + 1024) // [32][32] init-only alias
#define L_IPW3  L_KZ        // [32][128] init-only alias

__device__ const float ACO[5][5] = {
  { 0.2f, 0.f, 0.f, 0.f, 0.f },
  { (float)(3.0/40.0), (float)(9.0/40.0), 0.f, 0.f, 0.f },
  { (float)(44.0/45.0), (float)(-56.0/15.0), (float)(32.0/9.0), 0.f, 0.f },
  { (float)(19372.0/6561.0), (float)(-25360.0/2187.0), (float)(64448.0/6561.0), (float)(-212.0/729.0), 0.f },
  { (float)(9017.0/3168.0), (float)(-355.0/33.0), (float)(46732.0/5247.0), (float)(49.0/176.0), (float)(-5103.0/18656.0) }
};

#define B1C ((float)(35.0/384.0))
#define B3C ((float)(500.0/1113.0))
#define B4C ((float)(125.0/192.0))
#define B5C ((float)(-2187.0/6784.0))
#define B6C ((float)(11.0/84.0))

#define E1C ((float)(35.0/384.0 - 5179.0/57600.0))
#define E3C ((float)(500.0/1113.0 - 7571.0/16695.0))
#define E4C ((float)(125.0/192.0 - 393.0/640.0))
#define E5C ((float)(-2187.0/6784.0 + 92097.0/339200.0))
#define E6C ((float)(11.0/84.0 - 187.0/2100.0))
#define E7C ((float)(-1.0/40.0))

__device__ __forceinline__ f4 ld4(const float* p){ return *(const f4*)p; }
__device__ __forceinline__ void st4(float* p, f4 v){ *(f4*)p = v; }

// wave-local assemble: x = y + dtc*sum_p co[p]*k[p] -> XW[w] (k-major).
// No barriers: KZ rows 4w..4w+3 were written by this wave, XW read by this wave.
__device__ __forceinline__ void assemble_x(float* lds, int tid, float dtc,
                                           const float* co, int np)
{
  const int w = tid >> 6, lane = tid & 63;
  const int r = lane >> 4;            // 0..3 local row
  const int c = (lane << 1) & 31;     // even col
  const int o = (4 * w + r) * 36 + c;
  f2 y = *(const f2*)&lds[L_YZ + o];
  float sx = 0.f, sy = 0.f;
  for (int p = 0; p < np; p++){
    f2 kv = *(const f2*)&lds[L_KZ + p * 1152 + o];
    sx += co[p] * kv.x; sy += co[p] * kv.y;
  }
  float* XWp = &lds[L_XW + w * 128];
  XWp[(c + 0) * 4 + r] = y.x + dtc * sx;
  XWp[(c + 1) * 4 + r] = y.y + dtc * sy;
}

// full f-eval, wave-local: XW[w] -> KZ rows 4w..4w+3, KL rows 4w..4w+3.
// ZERO barriers: all phases are own-wave data (same-wave LDS ds ops are
// ordered by HW; cross-lane register returns get compiler waitcnts).
// Waves free-run and skew across stages -> VMEM stream of one wave
// overlaps VALU phases of others on the same SIMD.
__device__ void eval_f(float* lds, const float* __restrict__ ws, int tid,
                       float trP, int kout)
{
  const int w = tid >> 6, lane = tid & 63;
  const int cg = lane & 31, kh = lane >> 5;
  float* XWp = &lds[L_XW  + w * 128];
  float* H1p = &lds[L_H1W + w * 512];
  float* H2p = &lds[L_H2W + w * 512];

  // ---- issue first WR prefetch NOW: L2 latency hides under phase 1 ----
  const f4* WR4 = (const f4*)&ws[WS_WR];   // row k = 64 f4: [0:32)=W2T, [32:64)=R
  const int kb = kh * 64;
  f4 wb[4], rb[4];
#pragma unroll
  for (int u = 0; u < 4; u++){
    wb[u] = WR4[(kb + u) * 64 + cg];
    rb[u] = WR4[(kb + u) * 64 + 32 + cg];
  }

  // ---- phase 1: h1 = relu(x @ W1^T + b1) -> H1W[w] ; k split over halves ----
  float a1[4][4];
#pragma unroll
  for (int i = 0; i < 4; i++)
#pragma unroll
    for (int j = 0; j < 4; j++) a1[i][j] = 0.f;
#pragma unroll 4
  for (int t = 0; t < 16; t++){
    const int k = kh * 16 + t;
    f4 xv = ld4(&XWp[k * 4]);                       // broadcast (4 rows)
    f4 wv = ld4(&lds[L_W1T + k * 128 + 4 * cg]);
    const float* ap = (const float*)&xv;
    const float* bp = (const float*)&wv;
#pragma unroll
    for (int i = 0; i < 4; i++)
#pragma unroll
      for (int j = 0; j < 4; j++) a1[i][j] += bp[i] * ap[j];
  }
#pragma unroll
  for (int i = 0; i < 4; i++)
#pragma unroll
    for (int j = 0; j < 4; j++) a1[i][j] += __shfl_xor(a1[i][j], 32);
  if (kh == 0){
    f4 b1v = ld4(&lds[L_B1 + 4 * cg]);
    const float* b1p = (const float*)&b1v;
#pragma unroll
    for (int i = 0; i < 4; i++){
      f4 hv; float* hp = (float*)&hv;
#pragma unroll
      for (int j = 0; j < 4; j++) hp[j] = fmaxf(a1[i][j] + b1p[i], 0.f);
      st4(&H1p[(4 * cg + i) * 4], hv);
    }
  }
  // no barrier: H1W[w] consumed by same wave below (per-wave LDS ordering)

  // ---- phase 2: ah = h1@W2^T, at = m1^T R ; WR interleaved L2 stream ----
  float ah[4][4], at[4][4];
#pragma unroll
  for (int i = 0; i < 4; i++)
#pragma unroll
    for (int j = 0; j < 4; j++){ ah[i][j] = 0.f; at[i][j] = 0.f; }
#pragma unroll 1
  for (int g = 0; g < 16; g++){
    f4 wc[4], rc[4];
#pragma unroll
    for (int u = 0; u < 4; u++){ wc[u] = wb[u]; rc[u] = rb[u]; }
    if (g < 15){
      const int kn = kb + (g + 1) * 4;
#pragma unroll
      for (int u = 0; u < 4; u++){
        wb[u] = WR4[(kn + u) * 64 + cg];
        rb[u] = WR4[(kn + u) * 64 + 32 + cg];
      }
    }
#pragma unroll
    for (int u = 0; u < 4; u++){
      const int k = kb + g * 4 + u;
      f4 av = ld4(&H1p[k * 4]);                     // broadcast (4 rows)
      const float* ap = (const float*)&av;
      const float* wp = (const float*)&wc[u];
      const float* rp = (const float*)&rc[u];
      float m[4];
#pragma unroll
      for (int j = 0; j < 4; j++) m[j] = (ap[j] > 0.f) ? 1.f : 0.f;
#pragma unroll
      for (int i = 0; i < 4; i++)
#pragma unroll
        for (int j = 0; j < 4; j++){
          ah[i][j] += wp[i] * ap[j];
          at[i][j] += rp[i] * m[j];
        }
    }
  }
#pragma unroll
  for (int i = 0; i < 4; i++)
#pragma unroll
    for (int j = 0; j < 4; j++){
      ah[i][j] += __shfl_xor(ah[i][j], 32);
      at[i][j] += __shfl_xor(at[i][j], 32);
    }

  f4 b2v = ld4(&lds[L_B2 + 4 * cg]);
  const float* b2p = (const float*)&b2v;
  float h2v[4][4]; float dl[4] = {0.f, 0.f, 0.f, 0.f};
#pragma unroll
  for (int i = 0; i < 4; i++)
#pragma unroll
    for (int j = 0; j < 4; j++){
      float pre = ah[i][j] + b2p[i];
      float hv = fmaxf(pre, 0.f);
      h2v[i][j] = hv;
      if (pre > 0.f) dl[j] += at[i][j];
    }
#pragma unroll
  for (int mk = 1; mk < 32; mk <<= 1){
#pragma unroll
    for (int j = 0; j < 4; j++) dl[j] += __shfl_xor(dl[j], mk, 64);
  }
  if (kh == 0){
#pragma unroll
    for (int i = 0; i < 4; i++){
      f4 hv; float* hp = (float*)&hv;
#pragma unroll
      for (int j = 0; j < 4; j++) hp[j] = h2v[i][j];
      st4(&H2p[(4 * cg + i) * 4], hv);
    }
    if (cg == 0){
#pragma unroll
      for (int j = 0; j < 4; j++)
        lds[L_KL + kout * 32 + 4 * w + j] = dl[j] + trP;
    }
  }
  // no barrier: H2W[w] consumed by same wave below

  // ---- phase 3: dz = -(h2 @ C3 + c0 + x @ P) -> KZ rows of this wave ----
  float a3[4] = {0.f, 0.f, 0.f, 0.f};
  const int bb = kh * 64;
#pragma unroll 4
  for (int t = 0; t < 16; t++){
    f4 cv = ld4(&lds[L_C3T + cg * 132 + bb + 4 * t]);
    const float* cp = (const float*)&cv;
#pragma unroll
    for (int u = 0; u < 4; u++){
      f4 av = ld4(&H2p[(bb + 4 * t + u) * 4]);      // broadcast
      const float* ap = (const float*)&av;
#pragma unroll
      for (int j = 0; j < 4; j++) a3[j] += ap[j] * cp[u];
    }
  }
  const int qq = kh * 16;
#pragma unroll
  for (int t = 0; t < 4; t++){
    f4 pv = ld4(&lds[L_PT + cg * 36 + qq + 4 * t]);
    const float* pp = (const float*)&pv;
#pragma unroll
    for (int u = 0; u < 4; u++){
      f4 av = ld4(&XWp[(qq + 4 * t + u) * 4]);      // broadcast
      const float* ap = (const float*)&av;
#pragma unroll
      for (int j = 0; j < 4; j++) a3[j] += ap[j] * pp[u];
    }
  }
#pragma unroll
  for (int j = 0; j < 4; j++) a3[j] += __shfl_xor(a3[j], 32);
  if (kh == 0){
    float c0v = lds[L_C0 + cg];
#pragma unroll
    for (int j = 0; j < 4; j++)
      lds[L_KZ + kout * 1152 + (4 * w + j) * 36 + cg] = -(a3[j] + c0v);
  }
}

__global__ void __launch_bounds__(NT, 2)
qpnf_kernel(const float* __restrict__ z, const float* __restrict__ Gw,
            const float* __restrict__ W1g, const float* __restrict__ b1g,
            const float* __restrict__ W2g, const float* __restrict__ b2g,
            const float* __restrict__ W3g, const float* __restrict__ b3g,
            const float* __restrict__ Tg, float* __restrict__ out,
            float* __restrict__ ws)
{
  __shared__ float lds[LDS_FLOATS];
  const int tid = threadIdx.x;
  const int bid = blockIdx.x;
  const int r0 = bid * RB;
  cg::grid_group grid = cg::this_grid();

  // ================= init =================
  for (int i = 0; i < 8; i++){                // W1T[j][h] = W1[h][j]
    int idx = tid + i * NT;
    int h = idx >> 5, j = idx & 31;
    lds[L_W1T + j * 128 + h] = W1g[idx];
  }
  if (tid < 128){ lds[L_B1 + tid] = b1g[tid]; lds[L_B2 + tid] = b2g[tid]; }
  if (tid < 256) lds[L_GS + tid] = Gw[tid];
  __syncthreads();

  if (tid < 64){                              // A = G G^T (8x8), augmented
    int i = tid >> 3, j = tid & 7;
    float s = 0.f;
    for (int k = 0; k < 32; k++) s += lds[L_GS + i * 32 + k] * lds[L_GS + j * 32 + k];
    lds[L_AAUG + i * 16 + j] = s;
    lds[L_AAUG + i * 16 + 8 + j] = (i == j) ? 1.f : 0.f;
  }
  __syncthreads();
  if (tid == 0){                              // Gauss-Jordan, partial pivoting
    float* A = &lds[L_AAUG];
    for (int c = 0; c < 8; c++){
      int p = c; float mx = fabsf(A[c * 16 + c]);
      for (int r = c + 1; r < 8; r++){
        float v = fabsf(A[r * 16 + c]);
        if (v > mx){ mx = v; p = r; }
      }
      if (p != c)
        for (int q = 0; q < 16; q++){ float t = A[c*16+q]; A[c*16+q] = A[p*16+q]; A[p*16+q] = t; }
      float pv = 1.0f / A[c * 16 + c];
      for (int q = 0; q < 16; q++) A[c * 16 + q] *= pv;
      for (int r = 0; r < 8; r++) if (r != c){
        float fct = A[r * 16 + c];
        for (int q = 0; q < 16; q++) A[r * 16 + q] -= fct * A[c * 16 + q];
      }
    }
  }
  __syncthreads();
  if (tid < 256){                              // AinvG[m][d]
    int m = tid >> 5, d = tid & 31;
    float s = 0.f;
    for (int q = 0; q < 8; q++) s += lds[L_AAUG + m * 16 + 8 + q] * lds[L_GS + q * 32 + d];
    lds[L_AINVG + m * 32 + d] = s;
  }
  __syncthreads();
  for (int i4 = 0; i4 < 2; i4++){              // P = G^T AinvG (alias in H2W)
    int idx = tid + i4 * NT;
    int i = idx >> 5, j = idx & 31;
    float s = 0.f;
    for (int m = 0; m < 8; m++) s += lds[L_GS + m * 32 + i] * lds[L_AINVG + m * 32 + j];
    lds[L_P + i * 32 + j] = s;
  }
  __syncthreads();
  float* IPl = &lds[L_IP];                     // IP aliases H2W+1024 during init
  for (int i4 = 0; i4 < 2; i4++){
    int idx = tid + i4 * NT;
    int i = idx >> 5, j = idx & 31;
    IPl[i * 32 + j] = ((i == j) ? 1.f : 0.f) - lds[L_P + i * 32 + j];
  }
  if (tid == 0){
    float s = 0.f;
    for (int i = 0; i < 32; i++) s += lds[L_P + i * 32 + i];
    lds[L_MISC] = s;                           // trP
  }
  __syncthreads();
  for (int i4 = 0; i4 < 8; i4++){              // C3T[c][b] = sum_i W3[i][b] IP[i][c]
    int idx = tid + i4 * NT;
    int b = idx & 127, c = idx >> 7;
    float s = 0.f;
    for (int i = 0; i < 32; i++) s += W3g[i * 128 + b] * IPl[i * 32 + c];
    lds[L_C3T + c * 132 + b] = s;
  }
  for (int i4 = 0; i4 < 2; i4++){              // PT[c][q] = P[q][c]
    int idx = tid + i4 * NT;
    int c = idx >> 5, q = idx & 31;
    lds[L_PT + c * 36 + q] = lds[L_P + q * 32 + c];
  }
  if (tid < 32){                               // c0 = b3 @ IP
    float s = 0.f;
    for (int i = 0; i < 32; i++) s += b3g[i] * IPl[i * 32 + tid];
    lds[L_C0 + tid] = s;
  }
  for (int i4 = 0; i4 < 8; i4++){              // IPW3[j][b] (aliases KZ)
    int idx = tid + i4 * NT;
    int j = idx >> 7, b = idx & 127;
    float s = 0.f;
    for (int k = 0; k < 32; k++) s += IPl[j * 32 + k] * W3g[k * 128 + b];
    lds[L_IPW3 + j * 128 + b] = s;
  }
  __syncthreads();
  if (bid < 128 && tid < 128){                 // R row a=bid -> WR[a][128+b]
    int a = bid;
    float s = 0.f;
    for (int j = 0; j < 32; j++) s += W1g[a * 32 + j] * lds[L_IPW3 + j * 128 + tid];
    ws[WS_WR + a * 256 + 128 + tid] = s * W2g[tid * 128 + a];
  }
  if (bid >= 128 && tid < 128){                // W2T row a -> WR[a][b]
    int a = bid - 128;
    ws[WS_WR + a * 256 + tid] = W2g[tid * 128 + a];
  }
  if (tid < 256){                              // y0 = [z, 0] -> LDS
    const int r = tid >> 3, jj = (tid & 7) * 4;
    st4(&lds[L_YZ + r * 36 + jj], ld4(&z[(r0 + r) * 32 + jj]));
  }
  if (tid < RB) lds[L_YL + tid] = 0.f;

  const float trP = lds[L_MISC];
  const float t1 = 2.0f * Tg[0];

  grid.sync();

  // ================= main adaptive RK loop =================
  float t_cur = 0.f, dt_cur = 0.25f;
  bool prev_acc = false;

  for (int step = 0; step < 10; step++){
    if (t_cur >= t1 - 1e-9f) break;            // uniform across grid
    const float dtc = fminf(dt_cur, t1 - t_cur);

    // stages 1..6 — fully wave-local, NO barriers: waves free-run and skew
    for (int s = 1; s <= 6; s++){
      if (s == 1 && step > 0){
        if (prev_acc){                         // FSAL: k1 = previous k7 (wave-local)
          const int w = tid >> 6, lane = tid & 63;
          const int r = lane >> 4, c = (lane << 1) & 31;
          const int o = (4 * w + r) * 36 + c;
          *(f2*)&lds[L_KZ + o] = *(const f2*)&lds[L_KZ + 6 * 1152 + o];
          if (lane < 4) lds[L_KL + 4 * w + lane] = lds[L_KL + 6 * 32 + 4 * w + lane];
        }                                       // rejected: k1 = f(y) unchanged
        continue;
      }
      assemble_x(lds, tid, dtc, ACO[s >= 2 ? s - 2 : 0], s - 1);
      eval_f(lds, ws, tid, trP, s - 1);
    }

    // stage 7: y1, k7 = f(y1), error estimate
    __syncthreads();                           // all waves' KZ/KL visible
    if (tid < 256){
      const int r = tid >> 3, jj = (tid & 7) * 4;
      const int o = r * 36 + jj;
      f4 y   = ld4(&lds[L_YZ + o]);
      f4 k1v = ld4(&lds[L_KZ + 0 * 1152 + o]);
      f4 k3v = ld4(&lds[L_KZ + 2 * 1152 + o]);
      f4 k4v = ld4(&lds[L_KZ + 3 * 1152 + o]);
      f4 k5v = ld4(&lds[L_KZ + 4 * 1152 + o]);
      f4 k6v = ld4(&lds[L_KZ + 5 * 1152 + o]);
      f4 x;
      x.x = y.x + dtc * (B1C*k1v.x + B3C*k3v.x + B4C*k4v.x + B5C*k5v.x + B6C*k6v.x);
      x.y = y.y + dtc * (B1C*k1v.y + B3C*k3v.y + B4C*k4v.y + B5C*k5v.y + B6C*k6v.y);
      x.z = y.z + dtc * (B1C*k1v.z + B3C*k3v.z + B4C*k4v.z + B5C*k5v.z + B6C*k6v.z);
      x.w = y.w + dtc * (B1C*k1v.w + B3C*k3v.w + B4C*k4v.w + B5C*k5v.w + B6C*k6v.w);
      st4(&lds[L_Y1Z + o], x);
      float* XWp = &lds[L_XW + (r >> 2) * 128];   // scatter into owning wave's XW
      const int rr = r & 3;
      XWp[(jj + 0) * 4 + rr] = x.x;
      XWp[(jj + 1) * 4 + rr] = x.y;
      XWp[(jj + 2) * 4 + rr] = x.z;
      XWp[(jj + 3) * 4 + rr] = x.w;
    }
    if (tid < RB){
      float s = B1C * lds[L_KL + 0*32 + tid] + B3C * lds[L_KL + 2*32 + tid]
              + B4C * lds[L_KL + 3*32 + tid] + B5C * lds[L_KL + 4*32 + tid]
              + B6C * lds[L_KL + 5*32 + tid];
      lds[L_Y1L + tid] = lds[L_YL + tid] + dtc * s;
    }
    __syncthreads();                           // XW scatter was cross-wave
    eval_f(lds, ws, tid, trP, 6);
    __syncthreads();                           // all waves' k7 visible

    float sacc = 0.f;
    if (tid < 256){
      const int r = tid >> 3, jj = (tid & 7) * 4;
      const int o = r * 36 + jj;
      f4 k1v = ld4(&lds[L_KZ + 0 * 1152 + o]);
      f4 k3v = ld4(&lds[L_KZ + 2 * 1152 + o]);
      f4 k4v = ld4(&lds[L_KZ + 3 * 1152 + o]);
      f4 k5v = ld4(&lds[L_KZ + 4 * 1152 + o]);
      f4 k6v = ld4(&lds[L_KZ + 5 * 1152 + o]);
      f4 k7v = ld4(&lds[L_KZ + 6 * 1152 + o]);
      f4 yv  = ld4(&lds[L_YZ + o]);
      f4 y1v = ld4(&lds[L_Y1Z + o]);
      float ev, tol, q;
      ev = dtc * (E1C*k1v.x + E3C*k3v.x + E4C*k4v.x + E5C*k5v.x + E6C*k6v.x + E7C*k7v.x);
      tol = 1e-5f + 1e-5f * fmaxf(fabsf(yv.x), fabsf(y1v.x)); q = ev / tol; sacc += q * q;
      ev = dtc * (E1C*k1v.y + E3C*k3v.y + E4C*k4v.y + E5C*k5v.y + E6C*k6v.y + E7C*k7v.y);
      tol = 1e-5f + 1e-5f * fmaxf(fabsf(yv.y), fabsf(y1v.y)); q = ev / tol; sacc += q * q;
      ev = dtc * (E1C*k1v.z + E3C*k3v.z + E4C*k4v.z + E5C*k5v.z + E6C*k6v.z + E7C*k7v.z);
      tol = 1e-5f + 1e-5f * fmaxf(fabsf(yv.z), fabsf(y1v.z)); q = ev / tol; sacc += q * q;
      ev = dtc * (E1C*k1v.w + E3C*k3v.w + E4C*k4v.w + E5C*k5v.w + E6C*k6v.w + E7C*k7v.w);
      tol = 1e-5f + 1e-5f * fmaxf(fabsf(yv.w), fabsf(y1v.w)); q = ev / tol; sacc += q * q;
    }
    if (tid < RB){
      float evl = dtc * (E1C * lds[L_KL + 0*32 + tid] + E3C * lds[L_KL + 2*32 + tid]
                + E4C * lds[L_KL + 3*32 + tid] + E5C * lds[L_KL + 4*32 + tid]
                + E6C * lds[L_KL + 5*32 + tid] + E7C * lds[L_KL + 6*32 + tid]);
      float toll = 1e-5f + 1e-5f * fmaxf(fabsf(lds[L_YL + tid]), fabsf(lds[L_Y1L + tid]));
      float ql = evl / toll; sacc += ql * ql;
    }
    // block reduction: wave butterflies + 8-wide LDS combine
#pragma unroll
    for (int mk = 1; mk < 64; mk <<= 1) sacc += __shfl_xor(sacc, mk, 64);
    if ((tid & 63) == 0) lds[L_RED + (tid >> 6)] = sacc;   // RED aliases dead H1W
    __syncthreads();
    if (tid == 0){
      float s = lds[L_RED+0] + lds[L_RED+1] + lds[L_RED+2] + lds[L_RED+3]
              + lds[L_RED+4] + lds[L_RED+5] + lds[L_RED+6] + lds[L_RED+7];
      ws[WS_PART + step * 256 + bid] = s;
    }

    grid.sync();

    // deterministic global reduction (every block, identical order)
    float ps = 0.f;
    if (tid < 256) ps = ws[WS_PART + step * 256 + tid];
#pragma unroll
    for (int mk = 1; mk < 64; mk <<= 1) ps += __shfl_xor(ps, mk, 64);
    if (tid < 256 && (tid & 63) == 0) lds[L_RED + (tid >> 6)] = ps;
    __syncthreads();
    const float errn = sqrtf((lds[L_RED+0] + lds[L_RED+1] + lds[L_RED+2] + lds[L_RED+3])
                             / 270336.0f);
    __syncthreads();             // protect RED(=H1W) before next phase-1 overwrite

    const bool accept = (errn <= 1.0f);
    if (accept){                               // wave-local y <- y1
      const int w = tid >> 6, lane = tid & 63;
      const int r = lane >> 4, c = (lane << 1) & 31;
      const int o = (4 * w + r) * 36 + c;
      *(f2*)&lds[L_YZ + o] = *(const f2*)&lds[L_Y1Z + o];
      if (lane < 4) lds[L_YL + 4 * w + lane] = lds[L_Y1L + 4 * w + lane];
      t_cur += dtc;
    }
    float fac = 0.9f * powf(errn, -0.2f);
    fac = fminf(fmaxf(fac, 0.2f), 10.0f);
    dt_cur = fminf(fmaxf(dtc * fac, 1e-6f), t1);
    prev_acc = accept;
  }

  // ---- output: yT[:, :d] ----
  __syncthreads();
  if (tid < 256){
    const int r = tid >> 3, jj = (tid & 7) * 4;
    st4(&out[(r0 + r) * 32 + jj], ld4(&lds[L_YZ + r * 36 + jj]));
  }
}

extern "C" void kernel_launch(void* const* d_in, const int* in_sizes, int n_in,
                              void* d_out, int out_size, void* d_ws, size_t ws_size,
                              hipStream_t stream)
{
  (void)in_sizes; (void)n_in; (void)out_size;
  const float* z  = (const float*)d_in[0];
  const float* Gw = (const float*)d_in[1];
  const float* W1 = (const float*)d_in[2];
  const float* b1 = (const float*)d_in[3];
  const float* W2 = (const float*)d_in[4];
  const float* b2 = (const float*)d_in[5];
  const float* W3 = (const float*)d_in[6];
  const float* b3 = (const float*)d_in[7];
  const float* T  = (const float*)d_in[8];
  float* out = (float*)d_out;
  float* ws  = (float*)d_ws;
  if (ws_size < (size_t)WS_TOTAL * sizeof(float)) return;

  void* args[] = { (void*)&z, (void*)&Gw, (void*)&W1, (void*)&b1, (void*)&W2,
                   (void*)&b2, (void*)&W3, (void*)&b3, (void*)&T, (void*)&out,
                   (void*)&ws };
  hipLaunchCooperativeKernel((const void*)qpnf_kernel, dim3(256), dim3(NT),
                             args, 0, stream);
}